// Round 7
// baseline (89.717 us; speedup 1.0000x reference)
//
#include <hip/hip_runtime.h>

// FlashAttention fwd: B=2, S=2048, H=16, D=64, fp32 in/out, non-causal.
// R6: QT=256 (256 blocks, 512 thr, 8 waves x 32 q-rows), KVBLK=64,
// 4-buffer depth-3 prefetch with counted s_waitcnt vmcnt(4) + raw s_barrier
// (T4: loads stay in flight across barriers; no vmcnt(0) drain in loop).
// Compute = R5-verified: swapped QK^T 32x32 MFMA, in-register softmax
// (defer-max THR=8), P^T frags via permlane32_swap, V^T staged pre-swizzled.

#define S_  2048
#define HH  16
#define DD  64
#define QT  256
#define SR  1024   // H*D floats per token row
#define NT  32     // KV tiles of 64

typedef __attribute__((ext_vector_type(8)))  short short8;
typedef __attribute__((ext_vector_type(16))) float f32x16;
typedef __attribute__((ext_vector_type(2)))  unsigned uint2v;

__device__ __forceinline__ unsigned short f2bf(float f) {
    unsigned int u = __float_as_uint(f);
    u += 0x7fffu + ((u >> 16) & 1u);   // RNE
    return (unsigned short)(u >> 16);
}

__device__ __forceinline__ unsigned pkbf(float lo, float hi) {
    unsigned r;
    asm("v_cvt_pk_bf16_f32 %0, %1, %2" : "=v"(r) : "v"(lo), "v"(hi));
    return r;
}

__device__ __forceinline__ short8 cvt8(float4 a, float4 b) {
    union { unsigned u[4]; short8 v; } r;
    r.u[0] = pkbf(a.x, a.y); r.u[1] = pkbf(a.z, a.w);
    r.u[2] = pkbf(b.x, b.y); r.u[3] = pkbf(b.z, b.w);
    return r.v;
}

__device__ __forceinline__ f32x16 mfma32(short8 a, short8 b, f32x16 c) {
    return __builtin_amdgcn_mfma_f32_32x32x16_bf16(a, b, c, 0, 0, 0);
}

__device__ __forceinline__ void gload16(const void* g, void* l) {
    __builtin_amdgcn_global_load_lds(
        (const __attribute__((address_space(1))) void*)g,
        (__attribute__((address_space(3))) void*)l, 16, 0, 0);
}

__device__ __forceinline__ float mx3(float a, float b, float c) {
    return fmaxf(fmaxf(a, b), c);   // clang fuses to v_max3_f32
}

__device__ __forceinline__ void mk_pf(unsigned a, unsigned b,
                                      unsigned& lo, unsigned& hw, int hi) {
#if __has_builtin(__builtin_amdgcn_permlane32_swap)
    uint2v r = __builtin_amdgcn_permlane32_swap(a, b, false, false);
    lo = r[0]; hw = r[1];
#else
    unsigned rX = __shfl_xor(hi ? a : b, 32);
    lo = hi ? rX : a;
    hw = hi ? b  : rX;
#endif
}

// ---------------- prep kernels (R3-verified) ----------------

__global__ __launch_bounds__(256)
void prep_k(const float* __restrict__ k, short* __restrict__ kb) {
    const int gid = blockIdx.x * 256 + threadIdx.x;   // 524288 total
    const int d0 = (gid & 7) * 8;
    const int s  = (gid >> 3) & (S_ - 1);
    const int h  = (gid >> 14) & (HH - 1);
    const int b  = gid >> 18;
    const float* src = k + ((size_t)(b * S_ + s) * SR + h * DD + d0);
    float4 a = *(const float4*)src, bb = *(const float4*)(src + 4);
    *(short8*)&kb[((size_t)(b * HH + h) * S_ + s) * DD + d0] = cvt8(a, bb);
}

__global__ __launch_bounds__(256)
void prep_vt(const float* __restrict__ v, short* __restrict__ vt) {
    __shared__ short lt[64][72];   // +8 pad
    const int t = blockIdx.x & 31;
    const int h = (blockIdx.x >> 5) & 15;
    const int b = blockIdx.x >> 9;
    const int tid = threadIdx.x;
    const int c8 = tid & 7, r0 = tid >> 3;
    #pragma unroll
    for (int rr = 0; rr < 2; ++rr) {
        const int row = r0 + rr * 32;
        const float* src = v + ((size_t)(b * S_ + t * 64 + row) * SR + h * DD + c8 * 8);
        float4 a = *(const float4*)src, bb = *(const float4*)(src + 4);
        *(short8*)&lt[row][c8 * 8] = cvt8(a, bb);
    }
    __syncthreads();
    const int d = tid >> 2, q4 = tid & 3;
    short tmp[16];
    #pragma unroll
    for (int i = 0; i < 16; ++i) tmp[i] = lt[q4 * 16 + i][d];
    short8* dst = (short8*)&vt[((size_t)(b * HH + h) * DD + d) * S_ + t * 64 + q4 * 16];
    dst[0] = *(short8*)&tmp[0];
    dst[1] = *(short8*)&tmp[8];
}

// ---------------- main attention kernel ----------------

__global__ __launch_bounds__(512, 2)
void fattn_main(const float* __restrict__ q, const short* __restrict__ kb,
                const short* __restrict__ vtb, float* __restrict__ out) {
    // 4 buffers x (K 64x64 + V^T 64x64) bf16 = 64KB.
    // K[kv][d]: granule g holds 16B chunk g^(kv&7); V^T[d][kv]: g^(d&7).
    __shared__ short lk[4 * 4096];
    __shared__ short lvT[4 * 4096];

    const int tid  = threadIdx.x;
    const int lane = tid & 63;
    const int w    = tid >> 6;       // wave 0..7
    const int c    = lane & 31;
    const int hi   = lane >> 5;

    // XCD swizzle (256 = 8 XCDs x 32): 8 q-tile blocks of one (b,h) -> one XCD.
    const int bid0 = blockIdx.x;
    const int bid  = ((bid0 & 7) << 5) | (bid0 >> 3);
    const int qt  = bid & 7;
    const int h   = (bid >> 3) & 15;
    const int b   = bid >> 7;
    const int bh  = b * HH + h;

    const int qrow = qt * QT + w * 32 + c;
    const float sc = 0.125f * 1.4426950408889634f;  // D^-1/2 * log2(e)

    // ---- Q B-fragments: qf[kc][i] = Q[qrow][kc*16 + hi*8 + i] * sc ----
    short8 qf[4];
    {
        const float* qp = q + (size_t)(b * S_ + qrow) * SR + h * DD;
        #pragma unroll
        for (int kc = 0; kc < 4; ++kc) {
            const int d0 = kc * 16 + hi * 8;
            float4 a = *(const float4*)(qp + d0);
            float4 bb = *(const float4*)(qp + d0 + 4);
            a.x *= sc; a.y *= sc; a.z *= sc; a.w *= sc;
            bb.x *= sc; bb.y *= sc; bb.z *= sc; bb.w *= sc;
            qf[kc] = cvt8(a, bb);
        }
    }

    f32x16 o0, o1;
    #pragma unroll
    for (int i = 0; i < 16; ++i) { o0[i] = 0.f; o1[i] = 0.f; }
    float m_run = -1e30f, l_lane = 0.f;

    const short* kbh = kb  + (size_t)bh * S_ * DD;
    const short* vbh = vtb + (size_t)bh * DD * S_;
    const int r8 = lane >> 3;   // row within this wave's 8-row section
    const int g8 = lane & 7;    // granule
    const int row = w * 8 + r8; // kv-row (K) / d-row (V^T), sections by wave

    // Stage tile src_ into buffer dst_: 2 x global_load_lds per wave
    // (1KB each; whole block covers K 8KB + V 8KB). Pre-swizzled source.
    #define STAGE(src_, dst_)                                                    \
        do {                                                                     \
            gload16(kbh + (size_t)((src_) * 64 + row) * DD + ((g8 ^ r8) * 8),    \
                    &lk[(dst_) * 4096 + w * 512]);                               \
            gload16(vbh + (size_t)row * S_ + (src_) * 64 + ((g8 ^ r8) * 8),      \
                    &lvT[(dst_) * 4096 + w * 512]);                              \
        } while (0)

    STAGE(0, 0);
    STAGE(1, 1);
    STAGE(2, 2);   // 6 loads in flight (3 tiles x 2)

    for (int t = 0; t < NT; ++t) {
        // drain THIS tile's 2 loads (oldest); keep 4 newer in flight (T4)
        asm volatile("s_waitcnt vmcnt(4)" ::: "memory");
        __builtin_amdgcn_s_barrier();   // all waves: tile t staged, t-1 compute done
        {   // prefetch tile t+3 into buffer (t+3)&3 (its last reader was t-1)
            const int src = (t + 3 < NT) ? (t + 3) : (NT - 1);
            STAGE(src, (t + 3) & 3);
        }

        const short* lkS = &lk[(t & 3) * 4096];
        const short* lvS = &lvT[(t & 3) * 4096];

        // ---- S^T = K . Q^T : lane holds S[q=c][kv=(r&3)+8*(r>>2)+4*hi (+32)] ----
        f32x16 s0, s1;
        #pragma unroll
        for (int i = 0; i < 16; ++i) { s0[i] = 0.f; s1[i] = 0.f; }
        __builtin_amdgcn_s_setprio(1);
        #pragma unroll
        for (int kc = 0; kc < 4; ++kc) {
            const int ch = 2 * kc + hi;
            short8 kf0 = *(const short8*)&lkS[c * 64 + ((ch ^ (c & 7)) * 8)];
            short8 kf1 = *(const short8*)&lkS[(32 + c) * 64 + ((ch ^ (c & 7)) * 8)];
            s0 = mfma32(kf0, qf[kc], s0);
            s1 = mfma32(kf1, qf[kc], s1);
        }
        __builtin_amdgcn_s_setprio(0);

        // ---- pmax (max3 tree) ----
        float a0 = mx3(s0[0], s0[1], s0[2]),  a1 = mx3(s0[3], s0[4], s0[5]);
        float a2 = mx3(s0[6], s0[7], s0[8]),  a3 = mx3(s0[9], s0[10], s0[11]);
        float a4 = mx3(s0[12], s0[13], s0[14]);
        float a5 = mx3(s1[0], s1[1], s1[2]),  a6 = mx3(s1[3], s1[4], s1[5]);
        float a7 = mx3(s1[6], s1[7], s1[8]),  a8 = mx3(s1[9], s1[10], s1[11]);
        float a9 = mx3(s1[12], s1[13], s1[14]);
        float b0 = mx3(a0, a1, s0[15]), b1 = mx3(a2, a3, a4);
        float b2 = mx3(a5, a6, s1[15]), b3 = mx3(a7, a8, a9);
        float pmax = fmaxf(fmaxf(b0, b1), fmaxf(b2, b3));
        pmax = fmaxf(pmax, __shfl_xor(pmax, 32));

        if (__ballot(pmax > m_run + 8.0f)) {   // defer-max THR=8
            const float mn = fmaxf(m_run, pmax);
            const float corr = exp2f(m_run - mn);
            m_run = mn;
            l_lane *= corr;
            #pragma unroll
            for (int i = 0; i < 16; ++i) { o0[i] *= corr; o1[i] *= corr; }
        }

        // ---- exp2 -> pack -> in-register P^T frags -> PV ----
        float rs = 0.f;
        #pragma unroll
        for (int gidx = 0; gidx < 2; ++gidx) {
            const f32x16& sg = gidx ? s1 : s0;
            float p[16];
            #pragma unroll
            for (int i = 0; i < 16; ++i) p[i] = exp2f(sg[i] - m_run);
            rs += (((p[0] + p[1]) + (p[2] + p[3])) + ((p[4] + p[5]) + (p[6] + p[7])))
                + (((p[8] + p[9]) + (p[10] + p[11])) + ((p[12] + p[13]) + (p[14] + p[15])));
            unsigned pA[4], pB[4];
            #pragma unroll
            for (int sp = 0; sp < 4; ++sp) {
                pA[sp] = pkbf(p[4 * sp + 0], p[4 * sp + 1]);
                pB[sp] = pkbf(p[4 * sp + 2], p[4 * sp + 3]);
            }
            union PU { unsigned u[4]; short8 v; } pf[2];
            #pragma unroll
            for (int kcg = 0; kcg < 2; ++kcg) {
                unsigned loA, hwA, loB, hwB;
                mk_pf(pA[2 * kcg], pA[2 * kcg + 1], loA, hwA, hi);
                mk_pf(pB[2 * kcg], pB[2 * kcg + 1], loB, hwB, hi);
                pf[kcg].u[0] = loA; pf[kcg].u[1] = loB;
                pf[kcg].u[2] = hwA; pf[kcg].u[3] = hwB;
            }
            __builtin_amdgcn_s_setprio(1);
            #pragma unroll
            for (int kcg = 0; kcg < 2; ++kcg) {
                const int ch = 4 * gidx + 2 * kcg + hi;
                const int gsel = (ch ^ (c & 7)) * 8;
                short8 va0 = *(const short8*)&lvS[c * 64 + gsel];
                short8 va1 = *(const short8*)&lvS[(32 + c) * 64 + gsel];
                o0 = mfma32(va0, pf[kcg].v, o0);
                o1 = mfma32(va1, pf[kcg].v, o1);
            }
            __builtin_amdgcn_s_setprio(0);
        }
        l_lane += rs;   // cross-lane reduce deferred to epilogue
    }
    #undef STAGE

    // ---- Epilogue: O / l ----
    const float l_tot = l_lane + __shfl_xor(l_lane, 32);
    const float inv = 1.0f / l_tot;
    float* orow = out + (size_t)(b * S_ + qrow) * SR + h * DD;
    #pragma unroll
    for (int sp = 0; sp < 4; ++sp) {
        float4 st0, st1;
        st0.x = o0[4 * sp + 0] * inv; st0.y = o0[4 * sp + 1] * inv;
        st0.z = o0[4 * sp + 2] * inv; st0.w = o0[4 * sp + 3] * inv;
        st1.x = o1[4 * sp + 0] * inv; st1.y = o1[4 * sp + 1] * inv;
        st1.z = o1[4 * sp + 2] * inv; st1.w = o1[4 * sp + 3] * inv;
        *(float4*)(orow + 8 * sp + 4 * hi)      = st0;
        *(float4*)(orow + 32 + 8 * sp + 4 * hi) = st1;
    }
}

// ---------------- fallback (R2-verified, used if ws too small) ----------------

__global__ __launch_bounds__(256, 2)
void fattn_fb(const float* __restrict__ q, const float* __restrict__ k,
              const float* __restrict__ v, float* __restrict__ out) {
    __shared__ short lk[64 * DD];
    __shared__ short lvT[DD * 64];
    __shared__ short lp[4][32 * 64];

    const int tid  = threadIdx.x;
    const int lane = tid & 63;
    const int w    = tid >> 6;
    const int c    = lane & 31;
    const int hi   = lane >> 5;

    const int bid = blockIdx.x;
    const int qt  = bid & 15;
    const int h   = (bid >> 4) & 15;
    const int b   = bid >> 8;

    const int qrow = qt * 128 + w * 32 + c;
    const float sc = 0.125f * 1.4426950408889634f;

    short8 qf[4];
    {
        const float* qp = q + (size_t)(b * S_ + qrow) * SR + h * DD;
        #pragma unroll
        for (int kc = 0; kc < 4; ++kc) {
            const int d0 = kc * 16 + hi * 8;
            float4 a = *(const float4*)(qp + d0);
            float4 bb = *(const float4*)(qp + d0 + 4);
            a.x *= sc; a.y *= sc; a.z *= sc; a.w *= sc;
            bb.x *= sc; bb.y *= sc; bb.z *= sc; bb.w *= sc;
            qf[kc] = cvt8(a, bb);
        }
    }

    f32x16 o0, o1;
    #pragma unroll
    for (int i = 0; i < 16; ++i) { o0[i] = 0.f; o1[i] = 0.f; }
    float m_run = -1e30f, l_run = 0.f;

    const float* kb = k + (size_t)b * S_ * SR + h * DD;
    const float* vb = v + (size_t)b * S_ * SR + h * DD;

    for (int t = 0; t < S_ / 64; ++t) {
        __syncthreads();
        for (int cc = w; cc < 8; cc += 4) {
            const size_t gro = (size_t)(t * 64 + lane) * SR + cc * 8;
            const float4* kp = (const float4*)(kb + gro);
            float4 k0 = kp[0], k1 = kp[1];
            *(short8*)&lk[lane * 64 + ((cc ^ (lane & 7)) * 8)] = cvt8(k0, k1);
            const float4* vp = (const float4*)(vb + gro);
            float4 v0 = vp[0], v1 = vp[1];
            float vv[8] = {v0.x, v0.y, v0.z, v0.w, v1.x, v1.y, v1.z, v1.w};
            #pragma unroll
            for (int i = 0; i < 8; ++i) {
                const int d = cc * 8 + i;
                lvT[d * 64 + (((lane >> 3) ^ (d & 7)) * 8) + (lane & 7)] =
                    (short)f2bf(vv[i]);
            }
        }
        __syncthreads();

        f32x16 s0, s1;
        #pragma unroll
        for (int i = 0; i < 16; ++i) { s0[i] = 0.f; s1[i] = 0.f; }
        #pragma unroll
        for (int kc = 0; kc < 4; ++kc) {
            const int ch = 2 * kc + hi;
            short8 kf0 = *(const short8*)&lk[c * 64 + ((ch ^ (c & 7)) * 8)];
            short8 kf1 = *(const short8*)&lk[(32 + c) * 64 + ((ch ^ (c & 7)) * 8)];
            s0 = mfma32(kf0, qf[kc], s0);
            s1 = mfma32(kf1, qf[kc], s1);
        }

        float pmax = fmaxf(s0[0], s0[1]);
        #pragma unroll
        for (int i = 2; i < 16; ++i) pmax = fmaxf(pmax, s0[i]);
        #pragma unroll
        for (int i = 0; i < 16; ++i) pmax = fmaxf(pmax, s1[i]);
        pmax = fmaxf(pmax, __shfl_xor(pmax, 32));

        if (__ballot(pmax > m_run + 8.0f)) {
            const float mn = fmaxf(m_run, pmax);
            const float corr = exp2f(m_run - mn);
            m_run = mn;
            l_run *= corr;
            #pragma unroll
            for (int i = 0; i < 16; ++i) { o0[i] *= corr; o1[i] *= corr; }
        }

        float p0[16], p1[16];
        float rs = 0.f;
        #pragma unroll
        for (int i = 0; i < 16; ++i) { p0[i] = exp2f(s0[i] - m_run); rs += p0[i]; }
        #pragma unroll
        for (int i = 0; i < 16; ++i) { p1[i] = exp2f(s1[i] - m_run); rs += p1[i]; }
        rs += __shfl_xor(rs, 32);
        l_run += rs;

        #pragma unroll
        for (int sp = 0; sp < 4; ++sp) {
            uint2v w0;
            w0[0] = pkbf(p0[4 * sp + 0], p0[4 * sp + 1]);
            w0[1] = pkbf(p0[4 * sp + 2], p0[4 * sp + 3]);
            *(uint2v*)&lp[w][c * 64 + ((sp ^ (c & 7)) * 8) + hi * 4] = w0;
            uint2v w1;
            w1[0] = pkbf(p1[4 * sp + 0], p1[4 * sp + 1]);
            w1[1] = pkbf(p1[4 * sp + 2], p1[4 * sp + 3]);
            *(uint2v*)&lp[w][c * 64 + (((4 + sp) ^ (c & 7)) * 8) + hi * 4] = w1;
        }

        #pragma unroll
        for (int kc = 0; kc < 4; ++kc) {
            const int gsel = ((2 * kc + hi) ^ (c & 7)) * 8;
            short8 pa  = *(const short8*)&lp[w][c * 64 + gsel];
            short8 va0 = *(const short8*)&lvT[c * 64 + gsel];
            short8 va1 = *(const short8*)&lvT[(32 + c) * 64 + gsel];
            o0 = mfma32(va0, pa, o0);
            o1 = mfma32(va1, pa, o1);
        }
    }

    const float inv = 1.0f / l_run;
    float* orow = out + (size_t)(b * S_ + qrow) * SR + h * DD;
    #pragma unroll
    for (int sp = 0; sp < 4; ++sp) {
        float4 st0, st1;
        st0.x = o0[4 * sp + 0] * inv; st0.y = o0[4 * sp + 1] * inv;
        st0.z = o0[4 * sp + 2] * inv; st0.w = o0[4 * sp + 3] * inv;
        st1.x = o1[4 * sp + 0] * inv; st1.y = o1[4 * sp + 1] * inv;
        st1.z = o1[4 * sp + 2] * inv; st1.w = o1[4 * sp + 3] * inv;
        *(float4*)(orow + 8 * sp + 4 * hi)      = st0;
        *(float4*)(orow + 32 + 8 * sp + 4 * hi) = st1;
    }
}

extern "C" void kernel_launch(void* const* d_in, const int* in_sizes, int n_in,
                              void* d_out, int out_size, void* d_ws, size_t ws_size,
                              hipStream_t stream) {
    const float* q = (const float*)d_in[0];
    const float* k = (const float*)d_in[1];
    const float* v = (const float*)d_in[2];
    float* out = (float*)d_out;

    const size_t elems = (size_t)2 * HH * S_ * DD;       // 4.19M per tensor
    const size_t kvB   = elems * 2 * sizeof(short);      // Kb + VTb = 16.78 MB
    if (ws_size >= kvB) {
        short* kbuf  = (short*)d_ws;
        short* vtbuf = kbuf + elems;
        prep_k<<<dim3(2048), dim3(256), 0, stream>>>(k, kbuf);
        prep_vt<<<dim3(1024), dim3(256), 0, stream>>>(v, vtbuf);
        fattn_main<<<dim3(256), dim3(512), 0, stream>>>(q, kbuf, vtbuf, out);
    } else {
        fattn_fb<<<dim3(512), dim3(256), 0, stream>>>(q, k, v, out);
    }
}

// Round 8
// 80.243 us; speedup vs baseline: 1.1181x; 1.1181x over previous
//
#include <hip/hip_runtime.h>

// FlashAttention fwd: B=2, S=2048, H=16, D=64, fp32 in/out, non-causal.
// R7: two-tile software pipeline (T15): per iteration, QK^T(t+1) MFMAs are
// issued BEFORE softmax(t)+PV(t) so the QK MFMAs execute under softmax's
// VALU chain. Static A/B S-register alternation via 4x-unrolled body
// (4 LDS buffers, compile-time ds offsets). Staging = R6 counted vmcnt(2).
// Compute mappings = R5/R6-verified (swapped QK^T 32x32, in-reg softmax,
// permlane P^T frags, pre-swizzled K / V^T via global_load_lds).

#define S_  2048
#define HH  16
#define DD  64
#define QT  256
#define SR  1024   // H*D floats per token row
#define NT  32     // KV tiles of 64

typedef __attribute__((ext_vector_type(8)))  short short8;
typedef __attribute__((ext_vector_type(16))) float f32x16;
typedef __attribute__((ext_vector_type(2)))  unsigned uint2v;

__device__ __forceinline__ unsigned short f2bf(float f) {
    unsigned int u = __float_as_uint(f);
    u += 0x7fffu + ((u >> 16) & 1u);   // RNE
    return (unsigned short)(u >> 16);
}

__device__ __forceinline__ unsigned pkbf(float lo, float hi) {
    unsigned r;
    asm("v_cvt_pk_bf16_f32 %0, %1, %2" : "=v"(r) : "v"(lo), "v"(hi));
    return r;
}

__device__ __forceinline__ short8 cvt8(float4 a, float4 b) {
    union { unsigned u[4]; short8 v; } r;
    r.u[0] = pkbf(a.x, a.y); r.u[1] = pkbf(a.z, a.w);
    r.u[2] = pkbf(b.x, b.y); r.u[3] = pkbf(b.z, b.w);
    return r.v;
}

__device__ __forceinline__ f32x16 mfma32(short8 a, short8 b, f32x16 c) {
    return __builtin_amdgcn_mfma_f32_32x32x16_bf16(a, b, c, 0, 0, 0);
}

__device__ __forceinline__ void gload16(const void* g, void* l) {
    __builtin_amdgcn_global_load_lds(
        (const __attribute__((address_space(1))) void*)g,
        (__attribute__((address_space(3))) void*)l, 16, 0, 0);
}

__device__ __forceinline__ float mx3(float a, float b, float c) {
    return fmaxf(fmaxf(a, b), c);   // clang fuses to v_max3_f32
}

__device__ __forceinline__ void mk_pf(unsigned a, unsigned b,
                                      unsigned& lo, unsigned& hw, int hi) {
#if __has_builtin(__builtin_amdgcn_permlane32_swap)
    uint2v r = __builtin_amdgcn_permlane32_swap(a, b, false, false);
    lo = r[0]; hw = r[1];
#else
    unsigned rX = __shfl_xor(hi ? a : b, 32);
    lo = hi ? rX : a;
    hw = hi ? b  : rX;
#endif
}

// ---------------- prep kernels (R3-verified) ----------------

__global__ __launch_bounds__(256)
void prep_k(const float* __restrict__ k, short* __restrict__ kb) {
    const int gid = blockIdx.x * 256 + threadIdx.x;   // 524288 total
    const int d0 = (gid & 7) * 8;
    const int s  = (gid >> 3) & (S_ - 1);
    const int h  = (gid >> 14) & (HH - 1);
    const int b  = gid >> 18;
    const float* src = k + ((size_t)(b * S_ + s) * SR + h * DD + d0);
    float4 a = *(const float4*)src, bb = *(const float4*)(src + 4);
    *(short8*)&kb[((size_t)(b * HH + h) * S_ + s) * DD + d0] = cvt8(a, bb);
}

__global__ __launch_bounds__(256)
void prep_vt(const float* __restrict__ v, short* __restrict__ vt) {
    __shared__ short lt[64][72];   // +8 pad
    const int t = blockIdx.x & 31;
    const int h = (blockIdx.x >> 5) & 15;
    const int b = blockIdx.x >> 9;
    const int tid = threadIdx.x;
    const int c8 = tid & 7, r0 = tid >> 3;
    #pragma unroll
    for (int rr = 0; rr < 2; ++rr) {
        const int row = r0 + rr * 32;
        const float* src = v + ((size_t)(b * S_ + t * 64 + row) * SR + h * DD + c8 * 8);
        float4 a = *(const float4*)src, bb = *(const float4*)(src + 4);
        *(short8*)&lt[row][c8 * 8] = cvt8(a, bb);
    }
    __syncthreads();
    const int d = tid >> 2, q4 = tid & 3;
    short tmp[16];
    #pragma unroll
    for (int i = 0; i < 16; ++i) tmp[i] = lt[q4 * 16 + i][d];
    short8* dst = (short8*)&vt[((size_t)(b * HH + h) * DD + d) * S_ + t * 64 + q4 * 16];
    dst[0] = *(short8*)&tmp[0];
    dst[1] = *(short8*)&tmp[8];
}

// ---------------- main attention kernel ----------------

__global__ __launch_bounds__(512, 2)
void fattn_main(const float* __restrict__ q, const short* __restrict__ kb,
                const short* __restrict__ vtb, float* __restrict__ out) {
    // 4 buffers, each: K 64x64 bf16 (8KB) then V^T 64x64 bf16 (8KB). 64KB.
    // K[kv][d]: granule g holds 16B chunk g^(kv&7); V^T[d][kv]: g^(d&7).
    __shared__ short lds[4 * 8192];

    const int tid  = threadIdx.x;
    const int lane = tid & 63;
    const int w    = tid >> 6;       // wave 0..7
    const int c    = lane & 31;
    const int hi   = lane >> 5;

    // XCD swizzle (256 = 8 XCDs x 32)
    const int bid0 = blockIdx.x;
    const int bid  = ((bid0 & 7) << 5) | (bid0 >> 3);
    const int qt  = bid & 7;
    const int h   = (bid >> 3) & 15;
    const int b   = bid >> 7;
    const int bh  = b * HH + h;

    const int qrow = qt * QT + w * 32 + c;
    const float sc = 0.125f * 1.4426950408889634f;  // D^-1/2 * log2(e)

    // ---- Q B-fragments ----
    short8 qf[4];
    {
        const float* qp = q + (size_t)(b * S_ + qrow) * SR + h * DD;
        #pragma unroll
        for (int kc = 0; kc < 4; ++kc) {
            const int d0 = kc * 16 + hi * 8;
            float4 a = *(const float4*)(qp + d0);
            float4 bb = *(const float4*)(qp + d0 + 4);
            a.x *= sc; a.y *= sc; a.z *= sc; a.w *= sc;
            bb.x *= sc; bb.y *= sc; bb.z *= sc; bb.w *= sc;
            qf[kc] = cvt8(a, bb);
        }
    }

    f32x16 o0, o1;
    #pragma unroll
    for (int i = 0; i < 16; ++i) { o0[i] = 0.f; o1[i] = 0.f; }
    float m_run = -1e30f, l_lane = 0.f;

    const short* kbh = kb  + (size_t)bh * S_ * DD;
    const short* vbh = vtb + (size_t)bh * DD * S_;
    const int r8 = lane >> 3;
    const int g8 = lane & 7;
    const int row = w * 8 + r8;            // kv-row (K) / d-row (V^T)
    const int kswz = (g8 ^ r8) * 8;        // pre-swizzled source chunk

    // per-lane LDS byte offsets (lo rows c; hi rows 32+c add 4096 via imm)
    int aLo[4];
    #pragma unroll
    for (int j = 0; j < 4; ++j)
        aLo[j] = c * 128 + (((2 * j + hi) ^ (c & 7)) * 16);

    #define STAGE(src_, dstb_)                                                  \
        do {                                                                    \
            gload16(kbh + (size_t)((src_) * 64 + row) * DD + kswz,              \
                    &lds[(dstb_) * 8192 + w * 512]);                            \
            gload16(vbh + (size_t)row * S_ + (src_) * 64 + kswz,                \
                    &lds[(dstb_) * 8192 + 4096 + w * 512]);                     \
        } while (0)

    // K frag read: buffer B (compile-time), j, HI in {0,4096}
    #define LDK(B_, j_, HI_) \
        (*(const short8*)((const char*)lds + (B_) * 16384 + (HI_) + aLo[j_]))
    #define LDV(B_, j_, HI_) \
        (*(const short8*)((const char*)lds + (B_) * 16384 + 8192 + (HI_) + aLo[j_]))

    f32x16 s0A, s1A, s0B, s1B;

    // ---- prologue: stage 0,1,2; QK(0) -> A ----
    STAGE(0, 0); STAGE(1, 1); STAGE(2, 2);
    asm volatile("s_waitcnt vmcnt(4)" ::: "memory");   // tile 0 staged
    __builtin_amdgcn_s_barrier();
    #pragma unroll
    for (int i = 0; i < 16; ++i) { s0A[i] = 0.f; s1A[i] = 0.f; }
    __builtin_amdgcn_s_setprio(1);
    #pragma unroll
    for (int kc = 0; kc < 4; ++kc) {
        short8 kf0 = LDK(0, kc, 0);
        short8 kf1 = LDK(0, kc, 4096);
        s0A = mfma32(kf0, qf[kc], s0A);
        s1A = mfma32(kf1, qf[kc], s1A);
    }
    __builtin_amdgcn_s_setprio(0);

    // One pipeline body: tile T (S-regs SC*, V in buf BC), prefetch QK(T+1)
    // into SN* from buf BN. All buffer indices compile-time.
    #define BODY(T_, BC_, BN_, SC0, SC1, SN0, SN1)                              \
    do {                                                                        \
        asm volatile("s_waitcnt vmcnt(2)" ::: "memory");  /* tile T+1 staged */ \
        __builtin_amdgcn_s_barrier();                                           \
        { int ps = (T_) + 3; if (ps > NT - 1) ps = NT - 1;                      \
          STAGE(ps, ((T_) + 3) & 3); }                                          \
        /* ---- QK(T+1) -> SN (pure MFMA, overlaps SM below) ---- */            \
        _Pragma("unroll")                                                       \
        for (int i = 0; i < 16; ++i) { SN0[i] = 0.f; SN1[i] = 0.f; }            \
        __builtin_amdgcn_s_setprio(1);                                          \
        _Pragma("unroll")                                                       \
        for (int kc = 0; kc < 4; ++kc) {                                        \
            short8 kf0 = LDK(BN_, kc, 0);                                       \
            short8 kf1 = LDK(BN_, kc, 4096);                                    \
            SN0 = mfma32(kf0, qf[kc], SN0);                                     \
            SN1 = mfma32(kf1, qf[kc], SN1);                                     \
        }                                                                       \
        __builtin_amdgcn_s_setprio(0);                                          \
        /* ---- softmax(T) on SC ---- */                                        \
        float a0 = mx3(SC0[0], SC0[1], SC0[2]),  a1 = mx3(SC0[3], SC0[4], SC0[5]);  \
        float a2 = mx3(SC0[6], SC0[7], SC0[8]),  a3 = mx3(SC0[9], SC0[10], SC0[11]);\
        float a4 = mx3(SC0[12], SC0[13], SC0[14]);                              \
        float a5 = mx3(SC1[0], SC1[1], SC1[2]),  a6 = mx3(SC1[3], SC1[4], SC1[5]);  \
        float a7 = mx3(SC1[6], SC1[7], SC1[8]),  a8 = mx3(SC1[9], SC1[10], SC1[11]);\
        float a9 = mx3(SC1[12], SC1[13], SC1[14]);                              \
        float b0 = mx3(a0, a1, SC0[15]), b1 = mx3(a2, a3, a4);                  \
        float b2 = mx3(a5, a6, SC1[15]), b3 = mx3(a7, a8, a9);                  \
        float pmax = fmaxf(fmaxf(b0, b1), fmaxf(b2, b3));                       \
        pmax = fmaxf(pmax, __shfl_xor(pmax, 32));                               \
        if (__ballot(pmax > m_run + 8.0f)) {   /* defer-max THR=8 */            \
            const float mn = fmaxf(m_run, pmax);                                \
            const float corr = exp2f(m_run - mn);                               \
            m_run = mn;                                                         \
            l_lane *= corr;                                                     \
            _Pragma("unroll")                                                   \
            for (int i = 0; i < 16; ++i) { o0[i] *= corr; o1[i] *= corr; }      \
        }                                                                       \
        float rs = 0.f;                                                         \
        _Pragma("unroll")                                                       \
        for (int gidx = 0; gidx < 2; ++gidx) {                                  \
            const f32x16& sg = gidx ? SC1 : SC0;                                \
            float p[16];                                                        \
            _Pragma("unroll")                                                   \
            for (int i = 0; i < 16; ++i) p[i] = exp2f(sg[i] - m_run);           \
            rs += (((p[0] + p[1]) + (p[2] + p[3])) + ((p[4] + p[5]) + (p[6] + p[7])))   \
                + (((p[8] + p[9]) + (p[10] + p[11])) + ((p[12] + p[13]) + (p[14] + p[15]))); \
            unsigned pA[4], pB[4];                                              \
            _Pragma("unroll")                                                   \
            for (int sp = 0; sp < 4; ++sp) {                                    \
                pA[sp] = pkbf(p[4 * sp + 0], p[4 * sp + 1]);                    \
                pB[sp] = pkbf(p[4 * sp + 2], p[4 * sp + 3]);                    \
            }                                                                   \
            union PU { unsigned u[4]; short8 v; } pf[2];                        \
            _Pragma("unroll")                                                   \
            for (int kcg = 0; kcg < 2; ++kcg) {                                 \
                unsigned loA, hwA, loB, hwB;                                    \
                mk_pf(pA[2 * kcg], pA[2 * kcg + 1], loA, hwA, hi);              \
                mk_pf(pB[2 * kcg], pB[2 * kcg + 1], loB, hwB, hi);              \
                pf[kcg].u[0] = loA; pf[kcg].u[1] = loB;                         \
                pf[kcg].u[2] = hwA; pf[kcg].u[3] = hwB;                         \
            }                                                                   \
            /* ---- PV(T): j = 2*gidx + kcg ---- */                             \
            __builtin_amdgcn_s_setprio(1);                                      \
            _Pragma("unroll")                                                   \
            for (int kcg = 0; kcg < 2; ++kcg) {                                 \
                short8 va0 = LDV(BC_, 2 * gidx + kcg, 0);                       \
                short8 va1 = LDV(BC_, 2 * gidx + kcg, 4096);                    \
                o0 = mfma32(va0, pf[kcg].v, o0);                                \
                o1 = mfma32(va1, pf[kcg].v, o1);                                \
            }                                                                   \
            __builtin_amdgcn_s_setprio(0);                                      \
        }                                                                       \
        l_lane += rs;                                                           \
    } while (0)

    for (int t4 = 0; t4 < NT; t4 += 4) {
        BODY(t4 + 0, 0, 1, s0A, s1A, s0B, s1B);
        BODY(t4 + 1, 1, 2, s0B, s1B, s0A, s1A);
        BODY(t4 + 2, 2, 3, s0A, s1A, s0B, s1B);
        BODY(t4 + 3, 3, 0, s0B, s1B, s0A, s1A);
    }
    #undef BODY
    #undef STAGE

    // ---- Epilogue: O / l ----
    const float l_tot = l_lane + __shfl_xor(l_lane, 32);
    const float inv = 1.0f / l_tot;
    float* orow = out + (size_t)(b * S_ + qrow) * SR + h * DD;
    #pragma unroll
    for (int sp = 0; sp < 4; ++sp) {
        float4 st0, st1;
        st0.x = o0[4 * sp + 0] * inv; st0.y = o0[4 * sp + 1] * inv;
        st0.z = o0[4 * sp + 2] * inv; st0.w = o0[4 * sp + 3] * inv;
        st1.x = o1[4 * sp + 0] * inv; st1.y = o1[4 * sp + 1] * inv;
        st1.z = o1[4 * sp + 2] * inv; st1.w = o1[4 * sp + 3] * inv;
        *(float4*)(orow + 8 * sp + 4 * hi)      = st0;
        *(float4*)(orow + 32 + 8 * sp + 4 * hi) = st1;
    }
}

// ---------------- fallback (R2-verified, used if ws too small) ----------------

__global__ __launch_bounds__(256, 2)
void fattn_fb(const float* __restrict__ q, const float* __restrict__ k,
              const float* __restrict__ v, float* __restrict__ out) {
    __shared__ short lk[64 * DD];
    __shared__ short lvT[DD * 64];
    __shared__ short lp[4][32 * 64];

    const int tid  = threadIdx.x;
    const int lane = tid & 63;
    const int w    = tid >> 6;
    const int c    = lane & 31;
    const int hi   = lane >> 5;

    const int bid = blockIdx.x;
    const int qt  = bid & 15;
    const int h   = (bid >> 4) & 15;
    const int b   = bid >> 8;

    const int qrow = qt * 128 + w * 32 + c;
    const float sc = 0.125f * 1.4426950408889634f;
    typedef __attribute__((ext_vector_type(2))) unsigned uv2;

    short8 qf[4];
    {
        const float* qp = q + (size_t)(b * S_ + qrow) * SR + h * DD;
        #pragma unroll
        for (int kc = 0; kc < 4; ++kc) {
            const int d0 = kc * 16 + hi * 8;
            float4 a = *(const float4*)(qp + d0);
            float4 bb = *(const float4*)(qp + d0 + 4);
            a.x *= sc; a.y *= sc; a.z *= sc; a.w *= sc;
            bb.x *= sc; bb.y *= sc; bb.z *= sc; bb.w *= sc;
            qf[kc] = cvt8(a, bb);
        }
    }

    f32x16 o0, o1;
    #pragma unroll
    for (int i = 0; i < 16; ++i) { o0[i] = 0.f; o1[i] = 0.f; }
    float m_run = -1e30f, l_run = 0.f;

    const float* kb = k + (size_t)b * S_ * SR + h * DD;
    const float* vb = v + (size_t)b * S_ * SR + h * DD;

    for (int t = 0; t < S_ / 64; ++t) {
        __syncthreads();
        for (int cc = w; cc < 8; cc += 4) {
            const size_t gro = (size_t)(t * 64 + lane) * SR + cc * 8;
            const float4* kp = (const float4*)(kb + gro);
            float4 k0 = kp[0], k1 = kp[1];
            *(short8*)&lk[lane * 64 + ((cc ^ (lane & 7)) * 8)] = cvt8(k0, k1);
            const float4* vp = (const float4*)(vb + gro);
            float4 v0 = vp[0], v1 = vp[1];
            float vv[8] = {v0.x, v0.y, v0.z, v0.w, v1.x, v1.y, v1.z, v1.w};
            #pragma unroll
            for (int i = 0; i < 8; ++i) {
                const int d = cc * 8 + i;
                lvT[d * 64 + (((lane >> 3) ^ (d & 7)) * 8) + (lane & 7)] =
                    (short)f2bf(vv[i]);
            }
        }
        __syncthreads();

        f32x16 s0, s1;
        #pragma unroll
        for (int i = 0; i < 16; ++i) { s0[i] = 0.f; s1[i] = 0.f; }
        #pragma unroll
        for (int kc = 0; kc < 4; ++kc) {
            const int ch = 2 * kc + hi;
            short8 kf0 = *(const short8*)&lk[c * 64 + ((ch ^ (c & 7)) * 8)];
            short8 kf1 = *(const short8*)&lk[(32 + c) * 64 + ((ch ^ (c & 7)) * 8)];
            s0 = mfma32(kf0, qf[kc], s0);
            s1 = mfma32(kf1, qf[kc], s1);
        }

        float pmax = fmaxf(s0[0], s0[1]);
        #pragma unroll
        for (int i = 2; i < 16; ++i) pmax = fmaxf(pmax, s0[i]);
        #pragma unroll
        for (int i = 0; i < 16; ++i) pmax = fmaxf(pmax, s1[i]);
        pmax = fmaxf(pmax, __shfl_xor(pmax, 32));

        if (__ballot(pmax > m_run + 8.0f)) {
            const float mn = fmaxf(m_run, pmax);
            const float corr = exp2f(m_run - mn);
            m_run = mn;
            l_run *= corr;
            #pragma unroll
            for (int i = 0; i < 16; ++i) { o0[i] *= corr; o1[i] *= corr; }
        }

        float p0[16], p1[16];
        float rs = 0.f;
        #pragma unroll
        for (int i = 0; i < 16; ++i) { p0[i] = exp2f(s0[i] - m_run); rs += p0[i]; }
        #pragma unroll
        for (int i = 0; i < 16; ++i) { p1[i] = exp2f(s1[i] - m_run); rs += p1[i]; }
        rs += __shfl_xor(rs, 32);
        l_run += rs;

        #pragma unroll
        for (int sp = 0; sp < 4; ++sp) {
            uv2 w0;
            w0[0] = pkbf(p0[4 * sp + 0], p0[4 * sp + 1]);
            w0[1] = pkbf(p0[4 * sp + 2], p0[4 * sp + 3]);
            *(uv2*)&lp[w][c * 64 + ((sp ^ (c & 7)) * 8) + hi * 4] = w0;
            uv2 w1;
            w1[0] = pkbf(p1[4 * sp + 0], p1[4 * sp + 1]);
            w1[1] = pkbf(p1[4 * sp + 2], p1[4 * sp + 3]);
            *(uv2*)&lp[w][c * 64 + (((4 + sp) ^ (c & 7)) * 8) + hi * 4] = w1;
        }

        #pragma unroll
        for (int kc = 0; kc < 4; ++kc) {
            const int gsel = ((2 * kc + hi) ^ (c & 7)) * 8;
            short8 pa  = *(const short8*)&lp[w][c * 64 + gsel];
            short8 va0 = *(const short8*)&lvT[c * 64 + gsel];
            short8 va1 = *(const short8*)&lvT[(32 + c) * 64 + gsel];
            o0 = mfma32(va0, pa, o0);
            o1 = mfma32(va1, pa, o1);
        }
    }

    const float inv = 1.0f / l_run;
    float* orow = out + (size_t)(b * S_ + qrow) * SR + h * DD;
    #pragma unroll
    for (int sp = 0; sp < 4; ++sp) {
        float4 st0, st1;
        st0.x = o0[4 * sp + 0] * inv; st0.y = o0[4 * sp + 1] * inv;
        st0.z = o0[4 * sp + 2] * inv; st0.w = o0[4 * sp + 3] * inv;
        st1.x = o1[4 * sp + 0] * inv; st1.y = o1[4 * sp + 1] * inv;
        st1.z = o1[4 * sp + 2] * inv; st1.w = o1[4 * sp + 3] * inv;
        *(float4*)(orow + 8 * sp + 4 * hi)      = st0;
        *(float4*)(orow + 32 + 8 * sp + 4 * hi) = st1;
    }
}

extern "C" void kernel_launch(void* const* d_in, const int* in_sizes, int n_in,
                              void* d_out, int out_size, void* d_ws, size_t ws_size,
                              hipStream_t stream) {
    const float* q = (const float*)d_in[0];
    const float* k = (const float*)d_in[1];
    const float* v = (const float*)d_in[2];
    float* out = (float*)d_out;

    const size_t elems = (size_t)2 * HH * S_ * DD;       // 4.19M per tensor
    const size_t kvB   = elems * 2 * sizeof(short);      // Kb + VTb = 16.78 MB
    if (ws_size >= kvB) {
        short* kbuf  = (short*)d_ws;
        short* vtbuf = kbuf + elems;
        prep_k<<<dim3(2048), dim3(256), 0, stream>>>(k, kbuf);
        prep_vt<<<dim3(1024), dim3(256), 0, stream>>>(v, vtbuf);
        fattn_main<<<dim3(256), dim3(512), 0, stream>>>(q, kbuf, vtbuf, out);
    } else {
        fattn_fb<<<dim3(512), dim3(256), 0, stream>>>(q, k, v, out);
    }
}